// Round 2
// baseline (160.376 us; speedup 1.0000x reference)
//
#include <hip/hip_runtime.h>
#include <hip/hip_bf16.h>

// PraxisMemory: one-shot delta-rule memory. B=4,H=16,S=4096,D=64, all f32 I/O.
// k0: W0 -> bf16 transposed frags. k1: per (bh, S-chunk) partial
// M = sigma_k^T @ (V - (sigma_k@W0)/(sigma_k.z0)), z = colsum(sigma_k).
// k_reduce: sum partials + init, emit M^T bf16. k2: gated blend output.

#define B_  4
#define H_  16
#define S_  4096
#define D_  64
#define BH_ 64
#define EPS_ 1e-8f

typedef __attribute__((ext_vector_type(8))) short bf16x8;
typedef __attribute__((ext_vector_type(4))) float f32x4;
typedef __attribute__((ext_vector_type(4))) unsigned short u16x4;

__device__ __forceinline__ unsigned short f2bf(float x) {
    union { float f; unsigned u; } v; v.f = x;
    return (unsigned short)((v.u + 0x7FFFu + ((v.u >> 16) & 1u)) >> 16);  // RTNE
}
__device__ __forceinline__ float elup1(float x) {
    return x > 0.0f ? x + 1.0f : __expf(x);  // elu(x)+1
}
__device__ __forceinline__ f32x4 fzero() { f32x4 z = {0.f, 0.f, 0.f, 0.f}; return z; }

// ---------------------------------------------------------------------------
// k0: W0T[h][e*64+d] = bf16(W0[h][d*64+e])  (A-frag-ready transposed copy)
// ---------------------------------------------------------------------------
__global__ void k0_prep(const float* __restrict__ W0, unsigned short* __restrict__ W0T)
{
    const int h = blockIdx.x, t = threadIdx.x;
    #pragma unroll
    for (int i = 0; i < 16; ++i) {
        int o = i * 256 + t;            // output index e*64+d
        int e = o >> 6, d = o & 63;
        W0T[h * 4096 + o] = f2bf(W0[(size_t)h * 4096 + d * 64 + e]);
    }
}

// ---------------------------------------------------------------------------
// Kernel 1: per-(bh, split) partial states.
// 16x16x32 bf16 MFMA; A/B frag k-index bijection consistent on both operands.
// GEMM1 computed transposed: NUM^T = W0^T @ SK^T (den & V align per-lane).
// GEMM2: MP += SK^T @ VU via per-wave LDS transpose slabs.
// LDS: skT/vuT slabs overlaid (union) with the cross-wave M reduce buffer;
// total exactly 40960 B -> 4 blocks/CU.
// ---------------------------------------------------------------------------
__global__ __launch_bounds__(256, 4) void k1_states(
    const float* __restrict__ Kp, const float* __restrict__ Vp,
    const unsigned short* __restrict__ W0T, const float* __restrict__ Z0,
    float* __restrict__ Mpart, float* __restrict__ Zpart, int NS)
{
    const int bh = blockIdx.x / NS;
    const int p  = blockIdx.x % NS;
    const int h  = bh & (H_ - 1);
    const int tid  = threadIdx.x;
    const int lane = tid & 63;
    const int wave = tid >> 6;
    const int c16  = lane & 15;
    const int g4   = lane >> 4;

    // per-wave transpose slabs: [64 rows][40 shorts] (pitch 80B -> 16B-aligned b128)
    __shared__ __align__(16) union {
        struct { unsigned short skT[4][64][40], vuT[4][64][40]; } a;   // 40960 B
        struct { float M[64 * 65]; float Z[4][64]; } b;                // 17664 B
    } U;

    // z0 per-lane: z0v[kk][j] = Z0[h, kk*32 + g4*8 + j]
    float z0v[2][8];
    #pragma unroll
    for (int kk = 0; kk < 2; ++kk) {
        f32x4 a = *(const f32x4*)(Z0 + h * 64 + kk * 32 + g4 * 8);
        f32x4 b = *(const f32x4*)(Z0 + h * 64 + kk * 32 + g4 * 8 + 4);
        #pragma unroll
        for (int j = 0; j < 4; ++j) { z0v[kk][j] = a[j]; z0v[kk][4 + j] = b[j]; }
    }

    // W0^T A-fragments straight from bf16 transposed copy
    bf16x8 w0f[4][2];
    #pragma unroll
    for (int et = 0; et < 4; ++et)
    #pragma unroll
    for (int kk = 0; kk < 2; ++kk)
        w0f[et][kk] = *(const bf16x8*)(W0T + h * 4096 + (et * 16 + c16) * 64 + kk * 32 + g4 * 8);

    const size_t baseKV  = (size_t)bh * S_ * D_;
    const int    schunk  = S_ / NS;
    const int    ngroups = schunk / 32;

    f32x4 mpa[4][4];
    #pragma unroll
    for (int i = 0; i < 4; ++i)
    #pragma unroll
    for (int j = 0; j < 4; ++j) mpa[i][j] = fzero();
    float zacc[2][8];
    #pragma unroll
    for (int kk = 0; kk < 2; ++kk)
    #pragma unroll
    for (int j = 0; j < 8; ++j) zacc[kk][j] = 0.f;

    for (int g = wave; g < ngroups; g += 4) {
        const int row0 = p * schunk + g * 32;

        // ---- K rows -> sigma_k (B-frag-natural layout) ----
        float sk[2][2][8];
        #pragma unroll
        for (int st = 0; st < 2; ++st) {
            const float* kr = Kp + baseKV + (size_t)(row0 + st * 16 + c16) * D_;
            #pragma unroll
            for (int kk = 0; kk < 2; ++kk) {
                f32x4 a = *(const f32x4*)(kr + kk * 32 + g4 * 8);
                f32x4 b = *(const f32x4*)(kr + kk * 32 + g4 * 8 + 4);
                #pragma unroll
                for (int j = 0; j < 4; ++j) {
                    sk[st][kk][j]     = elup1(a[j]);
                    sk[st][kk][4 + j] = elup1(b[j]);
                }
            }
        }

        // ---- den = sigma_k . z0 ----
        float den0 = 0.f, den1 = 0.f;
        #pragma unroll
        for (int kk = 0; kk < 2; ++kk)
        #pragma unroll
        for (int j = 0; j < 8; ++j) {
            den0 += sk[0][kk][j] * z0v[kk][j];
            den1 += sk[1][kk][j] * z0v[kk][j];
        }
        den0 += __shfl_xor(den0, 16); den0 += __shfl_xor(den0, 32);
        den1 += __shfl_xor(den1, 16); den1 += __shfl_xor(den1, 32);
        const float rd0 = __builtin_amdgcn_rcpf(den0 + EPS_);
        const float rd1 = __builtin_amdgcn_rcpf(den1 + EPS_);

        // ---- z partial ----
        #pragma unroll
        for (int kk = 0; kk < 2; ++kk)
        #pragma unroll
        for (int j = 0; j < 8; ++j) zacc[kk][j] += sk[0][kk][j] + sk[1][kk][j];

        // ---- bf16 frags + skT transpose write (packed st0|st1 in one b32) ----
        bf16x8 skf[2][2];
        #pragma unroll
        for (int kk = 0; kk < 2; ++kk)
        #pragma unroll
        for (int j = 0; j < 8; ++j) {
            unsigned short b0 = f2bf(sk[0][kk][j]);
            unsigned short b1 = f2bf(sk[1][kk][j]);
            skf[0][kk][j] = (short)b0;
            skf[1][kk][j] = (short)b1;
            *(unsigned*)&U.a.skT[wave][kk * 32 + g4 * 8 + j][2 * c16] =
                (unsigned)b0 | ((unsigned)b1 << 16);
        }

        // ---- GEMM1^T: lane gets NUM[s=st*16+c16][e=et*16+g4*4+r] ----
        f32x4 acc[2][4];
        #pragma unroll
        for (int st = 0; st < 2; ++st)
        #pragma unroll
        for (int et = 0; et < 4; ++et) {
            f32x4 t = __builtin_amdgcn_mfma_f32_16x16x32_bf16(w0f[et][0], skf[st][0], fzero(), 0, 0, 0);
            acc[st][et] = __builtin_amdgcn_mfma_f32_16x16x32_bf16(w0f[et][1], skf[st][1], t, 0, 0, 0);
        }

        // ---- VU = V - NUM/den; write vuT ----
        const float* vr0 = Vp + baseKV + (size_t)(row0 + c16) * D_;
        const float* vr1 = Vp + baseKV + (size_t)(row0 + 16 + c16) * D_;
        #pragma unroll
        for (int et = 0; et < 4; ++et) {
            f32x4 v0 = *(const f32x4*)(vr0 + et * 16 + g4 * 4);
            f32x4 v1 = *(const f32x4*)(vr1 + et * 16 + g4 * 4);
            #pragma unroll
            for (int r = 0; r < 4; ++r) {
                float u0 = v0[r] - acc[0][et][r] * rd0;
                float u1 = v1[r] - acc[1][et][r] * rd1;
                *(unsigned*)&U.a.vuT[wave][et * 16 + g4 * 4 + r][2 * c16] =
                    (unsigned)f2bf(u0) | ((unsigned)f2bf(u1) << 16);
            }
        }

        // ---- GEMM2: MP += SK^T @ VU (wave-private LDS, same-wave lgkmcnt order) ----
        bf16x8 am[4], bn[4];
        #pragma unroll
        for (int mt = 0; mt < 4; ++mt)
            am[mt] = *(const bf16x8*)&U.a.skT[wave][mt * 16 + c16][g4 * 8];
        #pragma unroll
        for (int nt = 0; nt < 4; ++nt)
            bn[nt] = *(const bf16x8*)&U.a.vuT[wave][nt * 16 + c16][g4 * 8];
        #pragma unroll
        for (int mt = 0; mt < 4; ++mt)
        #pragma unroll
        for (int nt = 0; nt < 4; ++nt)
            mpa[mt][nt] = __builtin_amdgcn_mfma_f32_16x16x32_bf16(am[mt], bn[nt], mpa[mt][nt], 0, 0, 0);
    }

    // all waves done with U.a before overlaying U.b
    __syncthreads();

    // ---- z: reduce across c16 lanes ----
    #pragma unroll
    for (int kk = 0; kk < 2; ++kk)
    #pragma unroll
    for (int j = 0; j < 8; ++j) {
        float z = zacc[kk][j];
        z += __shfl_xor(z, 1); z += __shfl_xor(z, 2);
        z += __shfl_xor(z, 4); z += __shfl_xor(z, 8);
        if (c16 == 0) U.b.Z[wave][kk * 32 + g4 * 8 + j] = z;
    }

    // ---- serial deterministic cross-wave MP reduce ----
    for (int w = 0; w < 4; ++w) {
        if (wave == w) {
            #pragma unroll
            for (int mt = 0; mt < 4; ++mt)
            #pragma unroll
            for (int nt = 0; nt < 4; ++nt)
            #pragma unroll
            for (int r = 0; r < 4; ++r) {
                int idx = (mt * 16 + g4 * 4 + r) * 65 + nt * 16 + c16;
                float v = mpa[mt][nt][r];
                U.b.M[idx] = (w == 0) ? v : (U.b.M[idx] + v);
            }
        }
        __syncthreads();
    }

    float* mout = Mpart + ((size_t)p * BH_ + bh) * 4096;
    #pragma unroll
    for (int i = 0; i < 16; ++i) {
        int idx = i * 256 + tid;
        mout[idx] = U.b.M[(idx >> 6) * 65 + (idx & 63)];
    }
    if (tid < 64) {
        float zs = U.b.Z[0][tid] + U.b.Z[1][tid] + U.b.Z[2][tid] + U.b.Z[3][tid];
        Zpart[((size_t)p * BH_ + bh) * 64 + tid] = zs;
    }
}

// ---------------------------------------------------------------------------
// Reduce: M = W0 + sum_p Mpart -> MfinT bf16 [bh][e*64+d]; z = z0 + sum Zpart.
// Grid = BH_*4 blocks; block handles d-rows [q*16, q*16+16).
// ---------------------------------------------------------------------------
__global__ void k_reduce(const float* __restrict__ Mpart, const float* __restrict__ Zpart,
                         const float* __restrict__ W0, const float* __restrict__ Z0,
                         unsigned short* __restrict__ MfinT, float* __restrict__ Zfin, int NS)
{
    const int bh = blockIdx.x >> 2, q = blockIdx.x & 3;
    const int h = bh & (H_ - 1), t = threadIdx.x;
    __shared__ float Ml[16][65];

    const int o = q * 1024 + t * 4;          // linear d*64+e
    f32x4 s = *(const f32x4*)(W0 + (size_t)h * 4096 + o);
    for (int p = 0; p < NS; ++p)
        s = s + *(const f32x4*)(Mpart + ((size_t)p * BH_ + bh) * 4096 + o);
    const int dl = t >> 4, e0 = (t & 15) * 4;
    #pragma unroll
    for (int j = 0; j < 4; ++j) Ml[dl][e0 + j] = s[j];
    __syncthreads();

    const int e = t >> 2, dd0 = (t & 3) * 4;
    u16x4 w;
    #pragma unroll
    for (int j = 0; j < 4; ++j) w[j] = f2bf(Ml[dd0 + j][e]);
    *(u16x4*)(MfinT + (size_t)bh * 4096 + e * 64 + q * 16 + dd0) = w;

    if (q == 0 && t < 64) {
        float zs = Z0[h * 64 + t];
        for (int p = 0; p < NS; ++p) zs += Zpart[((size_t)p * BH_ + bh) * 64 + t];
        Zfin[bh * 64 + t] = zs;
    }
}

// ---------------------------------------------------------------------------
// Kernel 2: RET^T = M^T @ SQ^T ; out = O + gate*(RET/norm - O). No LDS.
// ---------------------------------------------------------------------------
__global__ __launch_bounds__(256, 4) void k2_out(
    const float* __restrict__ Qp, const float* __restrict__ Op,
    const float* __restrict__ Bp, const unsigned short* __restrict__ MfinT,
    const float* __restrict__ Zfin, float* __restrict__ Out, int NS2)
{
    const int bh = blockIdx.x / NS2;
    const int p  = blockIdx.x % NS2;
    const int h  = bh & (H_ - 1);
    const int tid = threadIdx.x, lane = tid & 63, wave = tid >> 6;
    const int c16 = lane & 15, g4 = lane >> 4;

    float mzv[2][8];
    #pragma unroll
    for (int kk = 0; kk < 2; ++kk) {
        f32x4 a = *(const f32x4*)(Zfin + bh * 64 + kk * 32 + g4 * 8);
        f32x4 b = *(const f32x4*)(Zfin + bh * 64 + kk * 32 + g4 * 8 + 4);
        #pragma unroll
        for (int j = 0; j < 4; ++j) { mzv[kk][j] = a[j]; mzv[kk][4 + j] = b[j]; }
    }

    bf16x8 mf[4][2];  // M^T A-frags, straight b128 loads
    #pragma unroll
    for (int et = 0; et < 4; ++et)
    #pragma unroll
    for (int kk = 0; kk < 2; ++kk)
        mf[et][kk] = *(const bf16x8*)(MfinT + (size_t)bh * 4096 + (et * 16 + c16) * 64 + kk * 32 + g4 * 8);

    float gate[4][4];
    #pragma unroll
    for (int et = 0; et < 4; ++et)
    #pragma unroll
    for (int r = 0; r < 4; ++r) {
        float b = Bp[h * 64 + et * 16 + g4 * 4 + r];
        gate[et][r] = 1.0f / (1.0f + __expf(-b));
    }

    const size_t base = (size_t)bh * S_ * D_;
    const int schunk = S_ / NS2, ngroups = schunk / 32;

    for (int g = wave; g < ngroups; g += 4) {
        const int row0 = p * schunk + g * 32;

        float sq[2][2][8];
        #pragma unroll
        for (int st = 0; st < 2; ++st) {
            const float* qr = Qp + base + (size_t)(row0 + st * 16 + c16) * D_;
            #pragma unroll
            for (int kk = 0; kk < 2; ++kk) {
                f32x4 a = *(const f32x4*)(qr + kk * 32 + g4 * 8);
                f32x4 b = *(const f32x4*)(qr + kk * 32 + g4 * 8 + 4);
                #pragma unroll
                for (int j = 0; j < 4; ++j) {
                    sq[st][kk][j]     = elup1(a[j]);
                    sq[st][kk][4 + j] = elup1(b[j]);
                }
            }
        }

        float n0 = 0.f, n1 = 0.f;
        #pragma unroll
        for (int kk = 0; kk < 2; ++kk)
        #pragma unroll
        for (int j = 0; j < 8; ++j) {
            n0 += sq[0][kk][j] * mzv[kk][j];
            n1 += sq[1][kk][j] * mzv[kk][j];
        }
        n0 += __shfl_xor(n0, 16); n0 += __shfl_xor(n0, 32);
        n1 += __shfl_xor(n1, 16); n1 += __shfl_xor(n1, 32);
        const float rn0 = __builtin_amdgcn_rcpf(n0 + EPS_);
        const float rn1 = __builtin_amdgcn_rcpf(n1 + EPS_);

        bf16x8 sqf[2][2];
        #pragma unroll
        for (int st = 0; st < 2; ++st)
        #pragma unroll
        for (int kk = 0; kk < 2; ++kk) {
            bf16x8 f;
            #pragma unroll
            for (int j = 0; j < 8; ++j) f[j] = (short)f2bf(sq[st][kk][j]);
            sqf[st][kk] = f;
        }

        f32x4 acc[2][4];
        #pragma unroll
        for (int st = 0; st < 2; ++st)
        #pragma unroll
        for (int et = 0; et < 4; ++et) {
            f32x4 t = __builtin_amdgcn_mfma_f32_16x16x32_bf16(mf[et][0], sqf[st][0], fzero(), 0, 0, 0);
            acc[st][et] = __builtin_amdgcn_mfma_f32_16x16x32_bf16(mf[et][1], sqf[st][1], t, 0, 0, 0);
        }

        #pragma unroll
        for (int st = 0; st < 2; ++st) {
            const float rn = st ? rn1 : rn0;
            const size_t roff = base + (size_t)(row0 + st * 16 + c16) * D_;
            #pragma unroll
            for (int et = 0; et < 4; ++et) {
                f32x4 o4 = *(const f32x4*)(Op + roff + et * 16 + g4 * 4);
                f32x4 w;
                #pragma unroll
                for (int r = 0; r < 4; ++r) {
                    float t = acc[st][et][r] * rn;
                    w[r] = o4[r] + gate[et][r] * (t - o4[r]);
                }
                *(f32x4*)(Out + roff + et * 16 + g4 * 4) = w;
            }
        }
    }
}

// ---------------------------------------------------------------------------
extern "C" void kernel_launch(void* const* d_in, const int* in_sizes, int n_in,
                              void* d_out, int out_size, void* d_ws, size_t ws_size,
                              hipStream_t stream)
{
    const float* Q  = (const float*)d_in[0];
    const float* K  = (const float*)d_in[1];
    const float* V  = (const float*)d_in[2];
    const float* O  = (const float*)d_in[3];
    const float* Bt = (const float*)d_in[4];
    const float* W0 = (const float*)d_in[5];
    const float* Z0 = (const float*)d_in[6];
    float* Out = (float*)d_out;

    // ws: [Mpart NS*64*4096 f32][Zpart NS*64*64 f32][Zfin 64*64 f32]
    //     [MfinT 64*4096 bf16][W0T 16*4096 bf16]
    int NS = 16;
    auto need = [](int ns) -> size_t {
        return sizeof(float) * ((size_t)ns * BH_ * 4096 + (size_t)ns * BH_ * 64 + BH_ * 64) +
               sizeof(unsigned short) * ((size_t)BH_ * 4096 + (size_t)H_ * 4096);
    };
    while (NS > 1 && need(NS) > ws_size) NS >>= 1;

    float* Mpart = (float*)d_ws;
    float* Zpart = Mpart + (size_t)NS * BH_ * 4096;
    float* Zfin  = Zpart + (size_t)NS * BH_ * 64;
    unsigned short* MfinT = (unsigned short*)(Zfin + (size_t)BH_ * 64);
    unsigned short* W0T   = MfinT + (size_t)BH_ * 4096;

    hipLaunchKernelGGL(k0_prep, dim3(H_), dim3(256), 0, stream, W0, W0T);
    hipLaunchKernelGGL(k1_states, dim3(BH_ * NS), dim3(256), 0, stream,
                       K, V, W0T, Z0, Mpart, Zpart, NS);
    hipLaunchKernelGGL(k_reduce, dim3(BH_ * 4), dim3(256), 0, stream,
                       Mpart, Zpart, W0, Z0, MfinT, Zfin, NS);
    hipLaunchKernelGGL(k2_out, dim3(BH_ * 16), dim3(256), 0, stream,
                       Q, O, Bt, MfinT, Zfin, Out, 16);
}

// Round 3
// 109.022 us; speedup vs baseline: 1.4710x; 1.4710x over previous
//
#include <hip/hip_runtime.h>
#include <hip/hip_bf16.h>

// PraxisMemory: one-shot delta-rule memory. B=4,H=16,S=4096,D=64, all f32 I/O.
// k0: W0 -> bf16 transposed frags. k1: per (bh, S-chunk) partial
// M = sigma_k^T @ (V - (sigma_k@W0)/(sigma_k.z0)), z = colsum(sigma_k).
// k_reduce: sum partials + init, emit M^T bf16. k2: gated blend output.
//
// k1 v3: block-cooperative GEMM2 — wave w owns d-tile mt=w (16 AGPR acc
// instead of 64), LDS slabs shared across waves with 2 barriers per
// 128-row tile. z via MFMA with ones-fragment. Target: no spill at
// 4 blocks/CU (launch_bounds(256,4), LDS 40960 B).

#define B_  4
#define H_  16
#define S_  4096
#define D_  64
#define BH_ 64
#define EPS_ 1e-8f

typedef __attribute__((ext_vector_type(8))) short bf16x8;
typedef __attribute__((ext_vector_type(4))) float f32x4;
typedef __attribute__((ext_vector_type(4))) unsigned short u16x4;

__device__ __forceinline__ unsigned short f2bf(float x) {
    union { float f; unsigned u; } v; v.f = x;
    return (unsigned short)((v.u + 0x7FFFu + ((v.u >> 16) & 1u)) >> 16);  // RTNE
}
__device__ __forceinline__ float elup1(float x) {
    return x > 0.0f ? x + 1.0f : __expf(x);  // elu(x)+1
}
__device__ __forceinline__ f32x4 fzero() { f32x4 z = {0.f, 0.f, 0.f, 0.f}; return z; }

// ---------------------------------------------------------------------------
// k0: W0T[h][e*64+d] = bf16(W0[h][d*64+e])  (A-frag-ready transposed copy)
// ---------------------------------------------------------------------------
__global__ void k0_prep(const float* __restrict__ W0, unsigned short* __restrict__ W0T)
{
    const int h = blockIdx.x, t = threadIdx.x;
    #pragma unroll
    for (int i = 0; i < 16; ++i) {
        int o = i * 256 + t;            // output index e*64+d
        int e = o >> 6, d = o & 63;
        W0T[h * 4096 + o] = f2bf(W0[(size_t)h * 4096 + d * 64 + e]);
    }
}

// ---------------------------------------------------------------------------
// Kernel 1: per-(bh, split) partial states.
// Per 128-row tile: wave w stages group w (sigma_k, VU transposes into
// shared slabs), barrier, then each wave computes its owned d-quadrant
// (mt=wave) of MP += SK^T @ VU over all 4 groups, plus z via ones-MFMA.
// ---------------------------------------------------------------------------
__global__ __launch_bounds__(256, 4) void k1_states(
    const float* __restrict__ Kp, const float* __restrict__ Vp,
    const unsigned short* __restrict__ W0T, const float* __restrict__ Z0,
    float* __restrict__ Mpart, float* __restrict__ Zpart, int NS)
{
    const int bh = blockIdx.x / NS;
    const int p  = blockIdx.x % NS;
    const int h  = bh & (H_ - 1);
    const int tid  = threadIdx.x;
    const int lane = tid & 63;
    const int wave = tid >> 6;
    const int c16  = lane & 15;
    const int g4   = lane >> 4;

    // shared transpose slabs: per group [64 rows][40 shorts] (pitch 80B)
    __shared__ __align__(16) unsigned short skT[4][64][40];   // 20480 B
    __shared__ __align__(16) unsigned short vuT[4][64][40];   // 20480 B

    // z0 per-lane: z0v[kk][j] = Z0[h, kk*32 + g4*8 + j]
    float z0v[2][8];
    #pragma unroll
    for (int kk = 0; kk < 2; ++kk) {
        f32x4 a = *(const f32x4*)(Z0 + h * 64 + kk * 32 + g4 * 8);
        f32x4 b = *(const f32x4*)(Z0 + h * 64 + kk * 32 + g4 * 8 + 4);
        #pragma unroll
        for (int j = 0; j < 4; ++j) { z0v[kk][j] = a[j]; z0v[kk][4 + j] = b[j]; }
    }

    // W0^T A-fragments straight from bf16 transposed copy
    bf16x8 w0f[4][2];
    #pragma unroll
    for (int et = 0; et < 4; ++et)
    #pragma unroll
    for (int kk = 0; kk < 2; ++kk)
        w0f[et][kk] = *(const bf16x8*)(W0T + h * 4096 + (et * 16 + c16) * 64 + kk * 32 + g4 * 8);

    bf16x8 ones;
    #pragma unroll
    for (int j = 0; j < 8; ++j) ones[j] = (short)0x3F80;  // bf16 1.0

    const size_t baseKV = (size_t)bh * S_ * D_;
    const int    schunk = S_ / NS;        // 256 at NS=16
    const int    iters  = schunk >> 7;    // 128 rows per tile

    f32x4 mpa[4];
    #pragma unroll
    for (int j = 0; j < 4; ++j) mpa[j] = fzero();
    f32x4 mpz = fzero();

    for (int it = 0; it < iters; ++it) {
        const int row0 = p * schunk + it * 128 + wave * 32;

        // ---- K rows -> sigma_k; den partial fused with load; bf16 frags ----
        float den0 = 0.f, den1 = 0.f;
        bf16x8 skf[2][2];
        #pragma unroll
        for (int st = 0; st < 2; ++st) {
            const float* kr = Kp + baseKV + (size_t)(row0 + st * 16 + c16) * D_;
            #pragma unroll
            for (int kk = 0; kk < 2; ++kk) {
                f32x4 a = *(const f32x4*)(kr + kk * 32 + g4 * 8);
                f32x4 b = *(const f32x4*)(kr + kk * 32 + g4 * 8 + 4);
                float d = 0.f;
                bf16x8 f;
                #pragma unroll
                for (int j = 0; j < 4; ++j) {
                    a[j] = elup1(a[j]); d += a[j] * z0v[kk][j];
                    b[j] = elup1(b[j]); d += b[j] * z0v[kk][4 + j];
                    f[j]     = (short)f2bf(a[j]);
                    f[4 + j] = (short)f2bf(b[j]);
                }
                skf[st][kk] = f;
                if (st == 0) den0 += d; else den1 += d;
            }
        }
        den0 += __shfl_xor(den0, 16); den0 += __shfl_xor(den0, 32);
        den1 += __shfl_xor(den1, 16); den1 += __shfl_xor(den1, 32);
        const float rd0 = __builtin_amdgcn_rcpf(den0 + EPS_);
        const float rd1 = __builtin_amdgcn_rcpf(den1 + EPS_);

        // ---- skT transpose write (packed st0|st1 in one b32) ----
        #pragma unroll
        for (int kk = 0; kk < 2; ++kk)
        #pragma unroll
        for (int j = 0; j < 8; ++j) {
            unsigned w = (unsigned)(unsigned short)skf[0][kk][j] |
                         ((unsigned)(unsigned short)skf[1][kk][j] << 16);
            *(unsigned*)&skT[wave][kk * 32 + g4 * 8 + j][2 * c16] = w;
        }

        // ---- per-et: GEMM1^T tiles + VU + vuT write (small live range) ----
        const float* vr0 = Vp + baseKV + (size_t)(row0 + c16) * D_;
        const float* vr1 = vr0 + 16 * D_;
        #pragma unroll
        for (int et = 0; et < 4; ++et) {
            f32x4 a0 = __builtin_amdgcn_mfma_f32_16x16x32_bf16(w0f[et][0], skf[0][0], fzero(), 0, 0, 0);
            a0 = __builtin_amdgcn_mfma_f32_16x16x32_bf16(w0f[et][1], skf[0][1], a0, 0, 0, 0);
            f32x4 a1 = __builtin_amdgcn_mfma_f32_16x16x32_bf16(w0f[et][0], skf[1][0], fzero(), 0, 0, 0);
            a1 = __builtin_amdgcn_mfma_f32_16x16x32_bf16(w0f[et][1], skf[1][1], a1, 0, 0, 0);
            f32x4 v0 = *(const f32x4*)(vr0 + et * 16 + g4 * 4);
            f32x4 v1 = *(const f32x4*)(vr1 + et * 16 + g4 * 4);
            #pragma unroll
            for (int r = 0; r < 4; ++r) {
                float u0 = v0[r] - a0[r] * rd0;
                float u1 = v1[r] - a1[r] * rd1;
                *(unsigned*)&vuT[wave][et * 16 + g4 * 4 + r][2 * c16] =
                    (unsigned)f2bf(u0) | ((unsigned)f2bf(u1) << 16);
            }
        }

        __syncthreads();

        // ---- GEMM2: wave owns mt=wave; iterate all 4 staged groups ----
        #pragma unroll
        for (int gg = 0; gg < 4; ++gg) {
            bf16x8 am = *(const bf16x8*)&skT[gg][wave * 16 + c16][g4 * 8];
            mpz = __builtin_amdgcn_mfma_f32_16x16x32_bf16(am, ones, mpz, 0, 0, 0);
            #pragma unroll
            for (int nt = 0; nt < 4; ++nt) {
                bf16x8 bn = *(const bf16x8*)&vuT[gg][nt * 16 + c16][g4 * 8];
                mpa[nt] = __builtin_amdgcn_mfma_f32_16x16x32_bf16(am, bn, mpa[nt], 0, 0, 0);
            }
        }

        __syncthreads();  // slabs reusable next tile
    }

    // ---- write partials: d = wave*16 + g4*4 + r, e = nt*16 + c16 ----
    float* mout = Mpart + ((size_t)p * BH_ + bh) * 4096;
    #pragma unroll
    for (int nt = 0; nt < 4; ++nt)
    #pragma unroll
    for (int r = 0; r < 4; ++r)
        mout[(wave * 16 + g4 * 4 + r) * 64 + nt * 16 + c16] = mpa[nt][r];

    if (c16 == 0) {
        #pragma unroll
        for (int r = 0; r < 4; ++r)
            Zpart[((size_t)p * BH_ + bh) * 64 + wave * 16 + g4 * 4 + r] = mpz[r];
    }
}

// ---------------------------------------------------------------------------
// Reduce: M = W0 + sum_p Mpart -> MfinT bf16 [bh][e*64+d]; z = z0 + sum Zpart.
// Grid = BH_*4 blocks; block handles d-rows [q*16, q*16+16).
// ---------------------------------------------------------------------------
__global__ void k_reduce(const float* __restrict__ Mpart, const float* __restrict__ Zpart,
                         const float* __restrict__ W0, const float* __restrict__ Z0,
                         unsigned short* __restrict__ MfinT, float* __restrict__ Zfin, int NS)
{
    const int bh = blockIdx.x >> 2, q = blockIdx.x & 3;
    const int h = bh & (H_ - 1), t = threadIdx.x;
    __shared__ float Ml[16][65];

    const int o = q * 1024 + t * 4;          // linear d*64+e
    f32x4 s = *(const f32x4*)(W0 + (size_t)h * 4096 + o);
    for (int p = 0; p < NS; ++p)
        s = s + *(const f32x4*)(Mpart + ((size_t)p * BH_ + bh) * 4096 + o);
    const int dl = t >> 4, e0 = (t & 15) * 4;
    #pragma unroll
    for (int j = 0; j < 4; ++j) Ml[dl][e0 + j] = s[j];
    __syncthreads();

    const int e = t >> 2, dd0 = (t & 3) * 4;
    u16x4 w;
    #pragma unroll
    for (int j = 0; j < 4; ++j) w[j] = f2bf(Ml[dd0 + j][e]);
    *(u16x4*)(MfinT + (size_t)bh * 4096 + e * 64 + q * 16 + dd0) = w;

    if (q == 0 && t < 64) {
        float zs = Z0[h * 64 + t];
        for (int p = 0; p < NS; ++p) zs += Zpart[((size_t)p * BH_ + bh) * 64 + t];
        Zfin[bh * 64 + t] = zs;
    }
}

// ---------------------------------------------------------------------------
// Kernel 2: RET^T = M^T @ SQ^T ; out = O + gate*(RET/norm - O). No LDS.
// ---------------------------------------------------------------------------
__global__ __launch_bounds__(256, 4) void k2_out(
    const float* __restrict__ Qp, const float* __restrict__ Op,
    const float* __restrict__ Bp, const unsigned short* __restrict__ MfinT,
    const float* __restrict__ Zfin, float* __restrict__ Out, int NS2)
{
    const int bh = blockIdx.x / NS2;
    const int p  = blockIdx.x % NS2;
    const int h  = bh & (H_ - 1);
    const int tid = threadIdx.x, lane = tid & 63, wave = tid >> 6;
    const int c16 = lane & 15, g4 = lane >> 4;

    float mzv[2][8];
    #pragma unroll
    for (int kk = 0; kk < 2; ++kk) {
        f32x4 a = *(const f32x4*)(Zfin + bh * 64 + kk * 32 + g4 * 8);
        f32x4 b = *(const f32x4*)(Zfin + bh * 64 + kk * 32 + g4 * 8 + 4);
        #pragma unroll
        for (int j = 0; j < 4; ++j) { mzv[kk][j] = a[j]; mzv[kk][4 + j] = b[j]; }
    }

    bf16x8 mf[4][2];  // M^T A-frags, straight b128 loads
    #pragma unroll
    for (int et = 0; et < 4; ++et)
    #pragma unroll
    for (int kk = 0; kk < 2; ++kk)
        mf[et][kk] = *(const bf16x8*)(MfinT + (size_t)bh * 4096 + (et * 16 + c16) * 64 + kk * 32 + g4 * 8);

    float gate[4][4];
    #pragma unroll
    for (int et = 0; et < 4; ++et)
    #pragma unroll
    for (int r = 0; r < 4; ++r) {
        float b = Bp[h * 64 + et * 16 + g4 * 4 + r];
        gate[et][r] = 1.0f / (1.0f + __expf(-b));
    }

    const size_t base = (size_t)bh * S_ * D_;
    const int schunk = S_ / NS2, ngroups = schunk / 32;

    for (int g = wave; g < ngroups; g += 4) {
        const int row0 = p * schunk + g * 32;

        float sq[2][2][8];
        #pragma unroll
        for (int st = 0; st < 2; ++st) {
            const float* qr = Qp + base + (size_t)(row0 + st * 16 + c16) * D_;
            #pragma unroll
            for (int kk = 0; kk < 2; ++kk) {
                f32x4 a = *(const f32x4*)(qr + kk * 32 + g4 * 8);
                f32x4 b = *(const f32x4*)(qr + kk * 32 + g4 * 8 + 4);
                #pragma unroll
                for (int j = 0; j < 4; ++j) {
                    sq[st][kk][j]     = elup1(a[j]);
                    sq[st][kk][4 + j] = elup1(b[j]);
                }
            }
        }

        float n0 = 0.f, n1 = 0.f;
        #pragma unroll
        for (int kk = 0; kk < 2; ++kk)
        #pragma unroll
        for (int j = 0; j < 8; ++j) {
            n0 += sq[0][kk][j] * mzv[kk][j];
            n1 += sq[1][kk][j] * mzv[kk][j];
        }
        n0 += __shfl_xor(n0, 16); n0 += __shfl_xor(n0, 32);
        n1 += __shfl_xor(n1, 16); n1 += __shfl_xor(n1, 32);
        const float rn0 = __builtin_amdgcn_rcpf(n0 + EPS_);
        const float rn1 = __builtin_amdgcn_rcpf(n1 + EPS_);

        bf16x8 sqf[2][2];
        #pragma unroll
        for (int st = 0; st < 2; ++st)
        #pragma unroll
        for (int kk = 0; kk < 2; ++kk) {
            bf16x8 f;
            #pragma unroll
            for (int j = 0; j < 8; ++j) f[j] = (short)f2bf(sq[st][kk][j]);
            sqf[st][kk] = f;
        }

        f32x4 acc[2][4];
        #pragma unroll
        for (int st = 0; st < 2; ++st)
        #pragma unroll
        for (int et = 0; et < 4; ++et) {
            f32x4 t = __builtin_amdgcn_mfma_f32_16x16x32_bf16(mf[et][0], sqf[st][0], fzero(), 0, 0, 0);
            acc[st][et] = __builtin_amdgcn_mfma_f32_16x16x32_bf16(mf[et][1], sqf[st][1], t, 0, 0, 0);
        }

        #pragma unroll
        for (int st = 0; st < 2; ++st) {
            const float rn = st ? rn1 : rn0;
            const size_t roff = base + (size_t)(row0 + st * 16 + c16) * D_;
            #pragma unroll
            for (int et = 0; et < 4; ++et) {
                f32x4 o4 = *(const f32x4*)(Op + roff + et * 16 + g4 * 4);
                f32x4 w;
                #pragma unroll
                for (int r = 0; r < 4; ++r) {
                    float t = acc[st][et][r] * rn;
                    w[r] = o4[r] + gate[et][r] * (t - o4[r]);
                }
                *(f32x4*)(Out + roff + et * 16 + g4 * 4) = w;
            }
        }
    }
}

// ---------------------------------------------------------------------------
extern "C" void kernel_launch(void* const* d_in, const int* in_sizes, int n_in,
                              void* d_out, int out_size, void* d_ws, size_t ws_size,
                              hipStream_t stream)
{
    const float* Q  = (const float*)d_in[0];
    const float* K  = (const float*)d_in[1];
    const float* V  = (const float*)d_in[2];
    const float* O  = (const float*)d_in[3];
    const float* Bt = (const float*)d_in[4];
    const float* W0 = (const float*)d_in[5];
    const float* Z0 = (const float*)d_in[6];
    float* Out = (float*)d_out;

    // ws: [Mpart NS*64*4096 f32][Zpart NS*64*64 f32][Zfin 64*64 f32]
    //     [MfinT 64*4096 bf16][W0T 16*4096 bf16]
    int NS = 16;
    auto need = [](int ns) -> size_t {
        return sizeof(float) * ((size_t)ns * BH_ * 4096 + (size_t)ns * BH_ * 64 + BH_ * 64) +
               sizeof(unsigned short) * ((size_t)BH_ * 4096 + (size_t)H_ * 4096);
    };
    while (NS > 1 && need(NS) > ws_size) NS >>= 1;

    float* Mpart = (float*)d_ws;
    float* Zpart = Mpart + (size_t)NS * BH_ * 4096;
    float* Zfin  = Zpart + (size_t)NS * BH_ * 64;
    unsigned short* MfinT = (unsigned short*)(Zfin + (size_t)BH_ * 64);
    unsigned short* W0T   = MfinT + (size_t)BH_ * 4096;

    hipLaunchKernelGGL(k0_prep, dim3(H_), dim3(256), 0, stream, W0, W0T);
    hipLaunchKernelGGL(k1_states, dim3(BH_ * NS), dim3(256), 0, stream,
                       K, V, W0T, Z0, Mpart, Zpart, NS);
    hipLaunchKernelGGL(k_reduce, dim3(BH_ * 4), dim3(256), 0, stream,
                       Mpart, Zpart, W0, Z0, MfinT, Zfin, NS);
    hipLaunchKernelGGL(k2_out, dim3(BH_ * 32), dim3(256), 0, stream,
                       Q, O, Bt, MfinT, Zfin, Out, 32);
}

// Round 4
// 89.183 us; speedup vs baseline: 1.7983x; 1.2225x over previous
//
#include <hip/hip_runtime.h>
#include <hip/hip_bf16.h>

// PraxisMemory: one-shot delta-rule memory. B=4,H=16,S=4096,D=64, all f32 I/O.
//
// Gram reformulation:  M = W0 + sigma_k^T @ VU
//                        = W0 + sigma_k^T @ V - (sigma_k^T diag(1/den) sigma_k) @ W0
//                        = W0 + MP1 - G @ W0
// k1: per (bh, S-chunk): accumulate MP1 (=sk^T@V), G (=sk^T sk/den), z (=colsum sk)
//     with pure gather loads + MFMA — no barriers, no staging LDS, max MLP.
//     Epilogue folds G@W0 (tiny 64x64x64) per block and writes Mpart = MP1 - G@W0.
// k_reduce: M = W0 + sum_p Mpart -> MfinT bf16; z = z0 + sum Zpart.
// k2: out = O + gate*(sq@M/norm - O).

#define B_  4
#define H_  16
#define S_  4096
#define D_  64
#define BH_ 64
#define EPS_ 1e-8f

typedef __attribute__((ext_vector_type(8))) short bf16x8;
typedef __attribute__((ext_vector_type(4))) float f32x4;
typedef __attribute__((ext_vector_type(4))) unsigned short u16x4;

__device__ __forceinline__ unsigned short f2bf(float x) {
    union { float f; unsigned u; } v; v.f = x;
    return (unsigned short)((v.u + 0x7FFFu + ((v.u >> 16) & 1u)) >> 16);  // RTNE
}
__device__ __forceinline__ float elup1(float x) {
    return x > 0.0f ? x + 1.0f : __expf(x);  // elu(x)+1
}
__device__ __forceinline__ f32x4 fzero() { f32x4 z = {0.f, 0.f, 0.f, 0.f}; return z; }

// ---------------------------------------------------------------------------
// Kernel 1: per-(bh, split) partials MP1, G, z; epilogue Mpart = MP1 - G@W0.
// MFMA 16x16x32 bf16 conventions (verified by passing rounds):
//   A-frag: lane m = l&15, per-lane k = (l>>4)*8 + j
//   B-frag: lane n = l&15, per-lane k = (l>>4)*8 + j   (same k bijection)
//   C/D:    lane l, reg r -> row m = (l>>4)*4 + r, col n = l&15
// Wave w owns output d-strip [16w,16w+16). Gather layout: lane (c16,g4) holds
// X[s = row0 + g4*8 + j][column]; strip q's column = ((wave+q)&3)*16 + c16 so
// q=0 is always the wave's own strip (compile-time register indexing).
// ---------------------------------------------------------------------------
__global__ __launch_bounds__(256, 4) void k1_states(
    const float* __restrict__ Kp, const float* __restrict__ Vp,
    const float* __restrict__ W0, const float* __restrict__ Z0,
    float* __restrict__ Mpart, float* __restrict__ Zpart, int NS)
{
    const int bh = blockIdx.x / NS;
    const int p  = blockIdx.x % NS;
    const int h  = bh & (H_ - 1);
    const int tid  = threadIdx.x;
    const int lane = tid & 63;
    const int wave = tid >> 6;
    const int c16  = lane & 15;
    const int g4   = lane >> 4;

    __shared__ float Glds[4][16][68];   // wave-private slabs (17 KiB)

    int   col[4];
    float z0l[4];
    #pragma unroll
    for (int q = 0; q < 4; ++q) {
        col[q] = (((wave + q) & 3) << 4) + c16;
        z0l[q] = Z0[h * 64 + col[q]];
    }

    bf16x8 ones;
    #pragma unroll
    for (int j = 0; j < 8; ++j) ones[j] = (short)0x3F80;  // bf16 1.0

    const size_t base   = (size_t)bh * S_ * D_;
    const int    schunk = S_ / NS;
    const int    nch    = schunk >> 5;   // 32-row chunks in this split

    f32x4 mp1[4], gac[4], zac = fzero();
    #pragma unroll
    for (int i = 0; i < 4; ++i) { mp1[i] = fzero(); gac[i] = fzero(); }

    #pragma unroll 1
    for (int c = wave; c < nch; c += 4) {
        const float* kr = Kp + base + (size_t)(p * schunk + c * 32) * D_;
        const float* vr = Vp + base + (size_t)(p * schunk + c * 32) * D_;

        // ---- gather K^T strips (independent loads -> deep MLP) ----
        float kf[4][8];
        #pragma unroll
        for (int q = 0; q < 4; ++q)
        #pragma unroll
        for (int j = 0; j < 8; ++j)
            kf[q][j] = kr[(g4 * 8 + j) * 64 + col[q]];

        // ---- sigma + den partials ----
        float den[8];
        #pragma unroll
        for (int j = 0; j < 8; ++j) den[j] = 0.f;
        #pragma unroll
        for (int q = 0; q < 4; ++q)
        #pragma unroll
        for (int j = 0; j < 8; ++j) {
            float s = elup1(kf[q][j]);
            kf[q][j] = s;
            den[j] += s * z0l[q];
        }
        // reduce den over the 16 lanes of each g4 group (full d sum)
        #pragma unroll
        for (int j = 0; j < 8; ++j) {
            float d = den[j];
            d += __shfl_xor(d, 1); d += __shfl_xor(d, 2);
            d += __shfl_xor(d, 4); d += __shfl_xor(d, 8);
            den[j] = __builtin_amdgcn_rcpf(d + EPS_);   // rd
        }

        // ---- fragments: own strip unscaled (A), all strips scaled (G's B) ----
        bf16x8 aown, skbS[4];
        #pragma unroll
        for (int j = 0; j < 8; ++j) aown[j] = (short)f2bf(kf[0][j]);
        #pragma unroll
        for (int q = 0; q < 4; ++q)
        #pragma unroll
        for (int j = 0; j < 8; ++j)
            skbS[q][j] = (short)f2bf(kf[q][j] * den[j]);

        // ---- gather V^T strips ----
        float vf[4][8];
        #pragma unroll
        for (int nt = 0; nt < 4; ++nt)
        #pragma unroll
        for (int j = 0; j < 8; ++j)
            vf[nt][j] = vr[(g4 * 8 + j) * 64 + nt * 16 + c16];
        bf16x8 vbf[4];
        #pragma unroll
        for (int nt = 0; nt < 4; ++nt)
        #pragma unroll
        for (int j = 0; j < 8; ++j) vbf[nt][j] = (short)f2bf(vf[nt][j]);

        // ---- 9 MFMAs ----
        zac = __builtin_amdgcn_mfma_f32_16x16x32_bf16(aown, ones, zac, 0, 0, 0);
        #pragma unroll
        for (int nt = 0; nt < 4; ++nt)
            mp1[nt] = __builtin_amdgcn_mfma_f32_16x16x32_bf16(aown, vbf[nt], mp1[nt], 0, 0, 0);
        #pragma unroll
        for (int q = 0; q < 4; ++q)
            gac[q] = __builtin_amdgcn_mfma_f32_16x16x32_bf16(aown, skbS[q], gac[q], 0, 0, 0);
    }

    // ================= epilogue (wave-private, barrier-free) =================
    // 1. G tiles -> LDS (cols at global d' position)
    #pragma unroll
    for (int q = 0; q < 4; ++q)
    #pragma unroll
    for (int r = 0; r < 4; ++r)
        Glds[wave][g4 * 4 + r][(((wave + q) & 3) << 4) + c16] = gac[q][r];

    // 2. read G back as A-frags: A[m=d(in-strip)][k=d']
    bf16x8 ag[2];
    #pragma unroll
    for (int kk = 0; kk < 2; ++kk)
    #pragma unroll
    for (int j = 0; j < 8; ++j)
        ag[kk][j] = (short)f2bf(Glds[wave][c16][kk * 32 + g4 * 8 + j]);

    // 3. GW0 tiles: B-frag from W0[d'][e] gathers (L2-resident, once per block)
    f32x4 gw[4];
    #pragma unroll
    for (int nt = 0; nt < 4; ++nt) {
        f32x4 t = fzero();
        #pragma unroll
        for (int kk = 0; kk < 2; ++kk) {
            bf16x8 wb;
            #pragma unroll
            for (int j = 0; j < 8; ++j)
                wb[j] = (short)f2bf(W0[(size_t)h * 4096 + (kk * 32 + g4 * 8 + j) * 64 + nt * 16 + c16]);
            t = __builtin_amdgcn_mfma_f32_16x16x32_bf16(ag[kk], wb, t, 0, 0, 0);
        }
        gw[nt] = t;
    }

    // 4. stage M slab (MP1 - GW0) in LDS, then fully-coalesced f32x4 stores
    #pragma unroll
    for (int nt = 0; nt < 4; ++nt)
    #pragma unroll
    for (int r = 0; r < 4; ++r)
        Glds[wave][g4 * 4 + r][nt * 16 + c16] = mp1[nt][r] - gw[nt][r];

    float* mout = Mpart + ((size_t)p * BH_ + bh) * 4096 + wave * 1024;
    #pragma unroll
    for (int q2 = 0; q2 < 4; ++q2) {
        f32x4 v = *(const f32x4*)&Glds[wave][q2 * 4 + g4][c16 * 4];
        *(f32x4*)(mout + q2 * 256 + lane * 4) = v;
    }

    // 5. z
    if (c16 == 0) {
        #pragma unroll
        for (int r = 0; r < 4; ++r)
            Zpart[((size_t)p * BH_ + bh) * 64 + wave * 16 + g4 * 4 + r] = zac[r];
    }
}

// ---------------------------------------------------------------------------
// Reduce: M = W0 + sum_p Mpart -> MfinT bf16 [bh][e*64+d]; z = z0 + sum Zpart.
// Grid = BH_*4 blocks; block handles d-rows [q*16, q*16+16).
// ---------------------------------------------------------------------------
__global__ void k_reduce(const float* __restrict__ Mpart, const float* __restrict__ Zpart,
                         const float* __restrict__ W0, const float* __restrict__ Z0,
                         unsigned short* __restrict__ MfinT, float* __restrict__ Zfin, int NS)
{
    const int bh = blockIdx.x >> 2, q = blockIdx.x & 3;
    const int h = bh & (H_ - 1), t = threadIdx.x;
    __shared__ float Ml[16][65];

    const int o = q * 1024 + t * 4;          // linear d*64+e
    f32x4 s = *(const f32x4*)(W0 + (size_t)h * 4096 + o);
    for (int p = 0; p < NS; ++p)
        s = s + *(const f32x4*)(Mpart + ((size_t)p * BH_ + bh) * 4096 + o);
    const int dl = t >> 4, e0 = (t & 15) * 4;
    #pragma unroll
    for (int j = 0; j < 4; ++j) Ml[dl][e0 + j] = s[j];
    __syncthreads();

    const int e = t >> 2, dd0 = (t & 3) * 4;
    u16x4 w;
    #pragma unroll
    for (int j = 0; j < 4; ++j) w[j] = f2bf(Ml[dd0 + j][e]);
    *(u16x4*)(MfinT + (size_t)bh * 4096 + e * 64 + q * 16 + dd0) = w;

    if (q == 0 && t < 64) {
        float zs = Z0[h * 64 + t];
        for (int p = 0; p < NS; ++p) zs += Zpart[((size_t)p * BH_ + bh) * 64 + t];
        Zfin[bh * 64 + t] = zs;
    }
}

// ---------------------------------------------------------------------------
// Kernel 2: RET^T = M^T @ SQ^T ; out = O + gate*(RET/norm - O). No LDS.
// ---------------------------------------------------------------------------
__global__ __launch_bounds__(256, 4) void k2_out(
    const float* __restrict__ Qp, const float* __restrict__ Op,
    const float* __restrict__ Bp, const unsigned short* __restrict__ MfinT,
    const float* __restrict__ Zfin, float* __restrict__ Out, int NS2)
{
    const int bh = blockIdx.x / NS2;
    const int p  = blockIdx.x % NS2;
    const int h  = bh & (H_ - 1);
    const int tid = threadIdx.x, lane = tid & 63, wave = tid >> 6;
    const int c16 = lane & 15, g4 = lane >> 4;

    float mzv[2][8];
    #pragma unroll
    for (int kk = 0; kk < 2; ++kk) {
        f32x4 a = *(const f32x4*)(Zfin + bh * 64 + kk * 32 + g4 * 8);
        f32x4 b = *(const f32x4*)(Zfin + bh * 64 + kk * 32 + g4 * 8 + 4);
        #pragma unroll
        for (int j = 0; j < 4; ++j) { mzv[kk][j] = a[j]; mzv[kk][4 + j] = b[j]; }
    }

    bf16x8 mf[4][2];  // M^T A-frags, straight b128 loads
    #pragma unroll
    for (int et = 0; et < 4; ++et)
    #pragma unroll
    for (int kk = 0; kk < 2; ++kk)
        mf[et][kk] = *(const bf16x8*)(MfinT + (size_t)bh * 4096 + (et * 16 + c16) * 64 + kk * 32 + g4 * 8);

    float gate[4][4];
    #pragma unroll
    for (int et = 0; et < 4; ++et)
    #pragma unroll
    for (int r = 0; r < 4; ++r) {
        float b = Bp[h * 64 + et * 16 + g4 * 4 + r];
        gate[et][r] = 1.0f / (1.0f + __expf(-b));
    }

    const size_t base = (size_t)bh * S_ * D_;
    const int schunk = S_ / NS2, ngroups = schunk / 32;

    for (int g = wave; g < ngroups; g += 4) {
        const int row0 = p * schunk + g * 32;

        float sq[2][2][8];
        #pragma unroll
        for (int st = 0; st < 2; ++st) {
            const float* qr = Qp + base + (size_t)(row0 + st * 16 + c16) * D_;
            #pragma unroll
            for (int kk = 0; kk < 2; ++kk) {
                f32x4 a = *(const f32x4*)(qr + kk * 32 + g4 * 8);
                f32x4 b = *(const f32x4*)(qr + kk * 32 + g4 * 8 + 4);
                #pragma unroll
                for (int j = 0; j < 4; ++j) {
                    sq[st][kk][j]     = elup1(a[j]);
                    sq[st][kk][4 + j] = elup1(b[j]);
                }
            }
        }

        float n0 = 0.f, n1 = 0.f;
        #pragma unroll
        for (int kk = 0; kk < 2; ++kk)
        #pragma unroll
        for (int j = 0; j < 8; ++j) {
            n0 += sq[0][kk][j] * mzv[kk][j];
            n1 += sq[1][kk][j] * mzv[kk][j];
        }
        n0 += __shfl_xor(n0, 16); n0 += __shfl_xor(n0, 32);
        n1 += __shfl_xor(n1, 16); n1 += __shfl_xor(n1, 32);
        const float rn0 = __builtin_amdgcn_rcpf(n0 + EPS_);
        const float rn1 = __builtin_amdgcn_rcpf(n1 + EPS_);

        bf16x8 sqf[2][2];
        #pragma unroll
        for (int st = 0; st < 2; ++st)
        #pragma unroll
        for (int kk = 0; kk < 2; ++kk) {
            bf16x8 f;
            #pragma unroll
            for (int j = 0; j < 8; ++j) f[j] = (short)f2bf(sq[st][kk][j]);
            sqf[st][kk] = f;
        }

        f32x4 acc[2][4];
        #pragma unroll
        for (int st = 0; st < 2; ++st)
        #pragma unroll
        for (int et = 0; et < 4; ++et) {
            f32x4 t = __builtin_amdgcn_mfma_f32_16x16x32_bf16(mf[et][0], sqf[st][0], fzero(), 0, 0, 0);
            acc[st][et] = __builtin_amdgcn_mfma_f32_16x16x32_bf16(mf[et][1], sqf[st][1], t, 0, 0, 0);
        }

        #pragma unroll
        for (int st = 0; st < 2; ++st) {
            const float rn = st ? rn1 : rn0;
            const size_t roff = base + (size_t)(row0 + st * 16 + c16) * D_;
            #pragma unroll
            for (int et = 0; et < 4; ++et) {
                f32x4 o4 = *(const f32x4*)(Op + roff + et * 16 + g4 * 4);
                f32x4 w;
                #pragma unroll
                for (int r = 0; r < 4; ++r) {
                    float t = acc[st][et][r] * rn;
                    w[r] = o4[r] + gate[et][r] * (t - o4[r]);
                }
                *(f32x4*)(Out + roff + et * 16 + g4 * 4) = w;
            }
        }
    }
}

// ---------------------------------------------------------------------------
extern "C" void kernel_launch(void* const* d_in, const int* in_sizes, int n_in,
                              void* d_out, int out_size, void* d_ws, size_t ws_size,
                              hipStream_t stream)
{
    const float* Q  = (const float*)d_in[0];
    const float* K  = (const float*)d_in[1];
    const float* V  = (const float*)d_in[2];
    const float* O  = (const float*)d_in[3];
    const float* Bt = (const float*)d_in[4];
    const float* W0 = (const float*)d_in[5];
    const float* Z0 = (const float*)d_in[6];
    float* Out = (float*)d_out;

    // ws: [Mpart NS*64*4096 f32][Zpart NS*64*64 f32][Zfin 64*64 f32][MfinT 64*4096 bf16]
    int NS = 16;
    auto need = [](int ns) -> size_t {
        return sizeof(float) * ((size_t)ns * BH_ * 4096 + (size_t)ns * BH_ * 64 + BH_ * 64) +
               sizeof(unsigned short) * (size_t)BH_ * 4096;
    };
    while (NS > 1 && need(NS) > ws_size) NS >>= 1;

    float* Mpart = (float*)d_ws;
    float* Zpart = Mpart + (size_t)NS * BH_ * 4096;
    float* Zfin  = Zpart + (size_t)NS * BH_ * 64;
    unsigned short* MfinT = (unsigned short*)(Zfin + (size_t)BH_ * 64);

    hipLaunchKernelGGL(k1_states, dim3(BH_ * NS), dim3(256), 0, stream,
                       K, V, W0, Z0, Mpart, Zpart, NS);
    hipLaunchKernelGGL(k_reduce, dim3(BH_ * 4), dim3(256), 0, stream,
                       Mpart, Zpart, W0, Z0, MfinT, Zfin, NS);
    hipLaunchKernelGGL(k2_out, dim3(BH_ * 32), dim3(256), 0, stream,
                       Q, O, Bt, MfinT, Zfin, Out, 32);
}